// Round 1
// baseline (93.922 us; speedup 1.0000x reference)
//
#include <hip/hip_runtime.h>

#define NUM_CLASSES 80
#define GTS 64

// One thread per (batch, point). Block = 256 points, gridDim.y = batch.
// Level boundaries in the point list are all multiples of 256, so every
// block is pyramid-level-uniform -> green/gray eligibility is a block-
// uniform 64-bit mask (one __ballot), and the g-loop only visits set bits.
__global__ __launch_bounds__(256) void lfd_assign(
    const float* __restrict__ points,
    const float* __restrict__ reg_ranges,
    const float* __restrict__ gray_ranges,
    const float* __restrict__ strides,
    const float* __restrict__ gt_bboxes,
    const int*  __restrict__ gt_labels,
    float* __restrict__ out_cls,
    float* __restrict__ out_reg,
    int P)
{
    __shared__ float4 sA[GTS];               // gx, gy, x2=(gx+gw)-1, y2=(gy+gh)-1
    __shared__ float4 sB[GTS];               // cx, cy, measure, 0
    __shared__ int    sL[GTS];               // labels
    __shared__ unsigned long long sCM[NUM_CLASSES]; // class -> gt bitmask
    __shared__ unsigned long long sGreen, sGray;

    const int tid = threadIdx.x;
    const int b   = blockIdx.y;
    const int p0  = blockIdx.x * 256;        // first point of this block (< P always)

    // Phase 1: stage gt boxes + labels
    if (tid < GTS) {
        const float4 bb = ((const float4*)gt_bboxes)[b * GTS + tid];
        const float gx = bb.x, gy = bb.y, gw = bb.z, gh = bb.w;
        float4 a, c;
        a.x = gx; a.y = gy;
        a.z = gx + gw - 1.0f;                // same assoc order as ref: (gx+gw)-1.0
        a.w = gy + gh - 1.0f;
        c.x = gx + gw * 0.5f;                // gw/2 is exact -> identical to ref
        c.y = gy + gh * 0.5f;
        c.z = fmaxf(gw, gh);                 // measure
        c.w = 0.0f;
        sA[tid] = a; sB[tid] = c;
        sL[tid] = gt_labels[b * GTS + tid];
    }
    __syncthreads();

    // Phase 2: block-uniform eligibility masks (wave 0) + class bitmasks
    if (tid < GTS) {
        const float meas = sB[tid].z;
        const float rlo = reg_ranges[p0 * 2], rhi = reg_ranges[p0 * 2 + 1];
        const float glo = gray_ranges[p0 * 2], ghi = gray_ranges[p0 * 2 + 1];
        const bool greenp = (rlo <= meas) && (meas <= rhi);
        const bool grayp  = ((glo <= meas) && (meas < rlo)) ||
                            ((rhi < meas) && (meas <= ghi));
        unsigned long long gm = __ballot(greenp);
        unsigned long long ym = __ballot(grayp);
        if (tid == 0) { sGreen = gm; sGray = ym; }
    } else if (tid < GTS + NUM_CLASSES) {
        const int c = tid - GTS;
        unsigned long long m = 0ull;
        #pragma unroll
        for (int g = 0; g < GTS; ++g)
            m |= (unsigned long long)(sL[g] == c) << g;
        sCM[c] = m;
    }
    __syncthreads();

    const int p = p0 + tid;
    if (p >= P) return;

    const float px = points[p * 2 + 0];
    const float py = points[p * 2 + 1];
    const float s2 = strides[p] * 0.5f;      // /2 exact
    const unsigned long long greenM = sGreen, grayM = sGray;

    unsigned long long hitM = 0ull;
    float best = 0.0f;
    int bestg = 0;

    // Wave-uniform sparse loop over eligible gts only
    unsigned long long m = greenM | grayM;
    while (m) {
        const int g = __builtin_ctzll(m);
        m &= m - 1;
        const float4 a = sA[g];
        const float d1 = px - a.x;
        const float d2 = py - a.y;
        const float d3 = a.z - px;
        const float d4 = a.w - py;
        const bool hit = fminf(fminf(d1, d2), fminf(d3, d4)) >= 0.0f;
        if (hit) {
            hitM |= 1ull << g;
            if ((greenM >> g) & 1ull) {
                const float lrmin = fminf(d1, d3), lrmax = fmaxf(d1, d3);
                const float tbmin = fminf(d2, d4), tbmax = fmaxf(d2, d4);
                // exact ref op order: (max(lrmin,0)/max(lrmax,.01)) * (...), then sqrt
                const float q1 = fmaxf(lrmin, 0.0f) / fmaxf(lrmax, 0.01f);
                const float q2 = fmaxf(tbmin, 0.0f) / fmaxf(tbmax, 0.01f);
                float s = sqrtf(q1 * q2);
                const float4 cc = sB[g];
                const bool core = (px >= cc.x - s2) && (px <= cc.x + s2) &&
                                  (py >= cc.y - s2) && (py <= cc.y + s2);
                if (core) s = 1.0f;
                if (s > best) { best = s; bestg = g; }  // strict > = first-idx ties
            }
        }
    }

    const bool pos = best > 0.0f;
    const int  ml  = sL[bestg];

    // reg output: raw delta at argmax, zeroed when !pos
    float4 r = make_float4(0.0f, 0.0f, 0.0f, 0.0f);
    if (pos) {
        const float4 a = sA[bestg];
        r.x = px - a.x; r.y = py - a.y; r.z = a.z - px; r.w = a.w - py;
    }
    ((float4*)out_reg)[(size_t)b * P + p] = r;

    // cls row: 80 floats, mostly zeros; -1 where a gray-hit gt has that class
    // (and the cell isn't the positive match), best at matched class when pos.
    const unsigned long long pg = hitM & grayM;
    float4* crow = (float4*)(out_cls + ((size_t)b * P + p) * NUM_CLASSES);
    #pragma unroll
    for (int c4 = 0; c4 < NUM_CLASSES / 4; ++c4) {
        float4 v;
        float* vv = (float*)&v;
        #pragma unroll
        for (int k = 0; k < 4; ++k) {
            const int c = c4 * 4 + k;
            float val = 0.0f;
            if ((pg & sCM[c]) != 0ull) val = -1.0f;
            if (pos && c == ml) val = best;   // best>0, so overrides -1 correctly
            vv[k] = val;
        }
        crow[c4] = v;
    }
}

extern "C" void kernel_launch(void* const* d_in, const int* in_sizes, int n_in,
                              void* d_out, int out_size, void* d_ws, size_t ws_size,
                              hipStream_t stream) {
    const float* points = (const float*)d_in[0];
    const float* rr     = (const float*)d_in[1];
    const float* gr     = (const float*)d_in[2];
    const float* st     = (const float*)d_in[3];
    const float* gtb    = (const float*)d_in[4];
    const int*   gtl    = (const int*)d_in[5];

    const int P = in_sizes[3];            // strides has P elements
    const int B = in_sizes[5] / GTS;      // gt_labels has B*64 elements

    float* out_cls = (float*)d_out;
    float* out_reg = out_cls + (size_t)B * P * NUM_CLASSES;

    dim3 grid((P + 255) / 256, B);
    hipLaunchKernelGGL(lfd_assign, grid, dim3(256), 0, stream,
                       points, rr, gr, st, gtb, gtl, out_cls, out_reg, P);
}

// Round 2
// 90.364 us; speedup vs baseline: 1.0394x; 1.0394x over previous
//
#include <hip/hip_runtime.h>

#define NUM_CLASSES 80
#define GTS 64

// One thread per (batch, point). Block = 256 points, gridDim.y = batch.
// Level boundaries in the point list are all multiples of 256, so every
// block is pyramid-level-uniform -> green/gray eligibility is a block-
// uniform 64-bit mask (one __ballot), and the g-loop only visits set bits.
//
// Epilogue is two-phase: per-point state -> LDS, then a coalesced sweep
// over the block's contiguous 256x80 cls region (64 consecutive float4
// per store instruction, vs 320B-strided scatter in the previous round).
__global__ __launch_bounds__(256) void lfd_assign(
    const float* __restrict__ points,
    const float* __restrict__ reg_ranges,
    const float* __restrict__ gray_ranges,
    const float* __restrict__ strides,
    const float* __restrict__ gt_bboxes,
    const int*  __restrict__ gt_labels,
    float* __restrict__ out_cls,
    float* __restrict__ out_reg,
    int P)
{
    __shared__ float4 sA[GTS];               // gx, gy, x2=(gx+gw)-1, y2=(gy+gh)-1
    __shared__ float4 sB[GTS];               // cx, cy, measure, 0
    __shared__ int    sL[GTS];               // labels
    __shared__ unsigned long long sCM[NUM_CLASSES]; // class -> gt bitmask
    __shared__ unsigned long long sGreen, sGray;
    // per-point epilogue state
    __shared__ unsigned long long sPG[256];  // hit & gray mask
    __shared__ float sBest[256];
    __shared__ int   sML[256];

    const int tid = threadIdx.x;
    const int b   = blockIdx.y;
    const int p0  = blockIdx.x * 256;        // first point of this block (< P always)

    // Phase 1: stage gt boxes + labels
    if (tid < GTS) {
        const float4 bb = ((const float4*)gt_bboxes)[b * GTS + tid];
        const float gx = bb.x, gy = bb.y, gw = bb.z, gh = bb.w;
        float4 a, c;
        a.x = gx; a.y = gy;
        a.z = gx + gw - 1.0f;                // same assoc order as ref: (gx+gw)-1.0
        a.w = gy + gh - 1.0f;
        c.x = gx + gw * 0.5f;                // gw/2 is exact -> identical to ref
        c.y = gy + gh * 0.5f;
        c.z = fmaxf(gw, gh);                 // measure
        c.w = 0.0f;
        sA[tid] = a; sB[tid] = c;
        sL[tid] = gt_labels[b * GTS + tid];
    }
    __syncthreads();

    // Phase 2: block-uniform eligibility masks (wave 0) + class bitmasks
    if (tid < GTS) {
        const float meas = sB[tid].z;
        const float rlo = reg_ranges[p0 * 2], rhi = reg_ranges[p0 * 2 + 1];
        const float glo = gray_ranges[p0 * 2], ghi = gray_ranges[p0 * 2 + 1];
        const bool greenp = (rlo <= meas) && (meas <= rhi);
        const bool grayp  = ((glo <= meas) && (meas < rlo)) ||
                            ((rhi < meas) && (meas <= ghi));
        unsigned long long gm = __ballot(greenp);
        unsigned long long ym = __ballot(grayp);
        if (tid == 0) { sGreen = gm; sGray = ym; }
    } else if (tid < GTS + NUM_CLASSES) {
        const int c = tid - GTS;
        unsigned long long m = 0ull;
        #pragma unroll
        for (int g = 0; g < GTS; ++g)
            m |= (unsigned long long)(sL[g] == c) << g;
        sCM[c] = m;
    }
    __syncthreads();

    const int p = p0 + tid;

    unsigned long long hitM = 0ull;
    float best = 0.0f;
    int bestg = 0;

    if (p < P) {
        const float2 pxy = ((const float2*)points)[p];
        const float px = pxy.x, py = pxy.y;
        const float s2 = strides[p] * 0.5f;  // /2 exact
        const unsigned long long greenM = sGreen, grayM = sGray;

        // Wave-uniform sparse loop over eligible gts only
        unsigned long long m = greenM | grayM;
        while (m) {
            const int g = __builtin_ctzll(m);
            m &= m - 1;
            const float4 a = sA[g];
            const float d1 = px - a.x;
            const float d2 = py - a.y;
            const float d3 = a.z - px;
            const float d4 = a.w - py;
            const bool hit = fminf(fminf(d1, d2), fminf(d3, d4)) >= 0.0f;
            if (hit) {
                hitM |= 1ull << g;
                if ((greenM >> g) & 1ull) {
                    const float lrmin = fminf(d1, d3), lrmax = fmaxf(d1, d3);
                    const float tbmin = fminf(d2, d4), tbmax = fmaxf(d2, d4);
                    // exact ref op order: (max/max)*(max/max), then sqrt
                    const float q1 = fmaxf(lrmin, 0.0f) / fmaxf(lrmax, 0.01f);
                    const float q2 = fmaxf(tbmin, 0.0f) / fmaxf(tbmax, 0.01f);
                    float s = sqrtf(q1 * q2);
                    const float4 cc = sB[g];
                    const bool core = (px >= cc.x - s2) && (px <= cc.x + s2) &&
                                      (py >= cc.y - s2) && (py <= cc.y + s2);
                    if (core) s = 1.0f;
                    if (s > best) { best = s; bestg = g; }  // strict > = first-idx ties
                }
            }
        }

        // reg output: raw delta at argmax, zeroed when !pos (already coalesced:
        // lane-consecutive float4)
        const bool pos = best > 0.0f;
        float4 r = make_float4(0.0f, 0.0f, 0.0f, 0.0f);
        if (pos) {
            const float4 a = sA[bestg];
            r.x = px - a.x; r.y = py - a.y; r.z = a.z - px; r.w = a.w - py;
        }
        ((float4*)out_reg)[(size_t)b * P + p] = r;
    }

    sPG[tid]   = hitM & sGray;
    sBest[tid] = best;
    sML[tid]   = sL[bestg];
    __syncthreads();

    // Phase 3: coalesced cls sweep. Block's cls region = nvalid*80 floats,
    // contiguous. nvalid is 256 for all blocks except the last (64), so
    // nf4 = nvalid*20 is a multiple of 256 -> uniform loop bound.
    const int nvalid = min(256, P - p0);
    const int nf4 = nvalid * 20;             // float4s in this block's region
    float4* crow = (float4*)(out_cls + ((size_t)b * P + p0) * NUM_CLASSES);

    for (int f4 = tid; f4 < nf4; f4 += 256) {
        const int pt = f4 / 20;              // local point index
        const int c4 = f4 - pt * 20;         // float4 index within the row
        const unsigned long long pgv = sPG[pt];
        const float bv = sBest[pt];
        const int   mlv = sML[pt];
        const bool  posv = bv > 0.0f;
        float4 v;
        float* vv = (float*)&v;
        #pragma unroll
        for (int k = 0; k < 4; ++k) {
            const int c = c4 * 4 + k;
            float val = 0.0f;
            if ((pgv & sCM[c]) != 0ull) val = -1.0f;
            if (posv && c == mlv) val = bv;  // best>0 overrides -1 correctly
            vv[k] = val;
        }
        crow[f4] = v;
    }
}

extern "C" void kernel_launch(void* const* d_in, const int* in_sizes, int n_in,
                              void* d_out, int out_size, void* d_ws, size_t ws_size,
                              hipStream_t stream) {
    const float* points = (const float*)d_in[0];
    const float* rr     = (const float*)d_in[1];
    const float* gr     = (const float*)d_in[2];
    const float* st     = (const float*)d_in[3];
    const float* gtb    = (const float*)d_in[4];
    const int*   gtl    = (const int*)d_in[5];

    const int P = in_sizes[3];            // strides has P elements
    const int B = in_sizes[5] / GTS;      // gt_labels has B*64 elements

    float* out_cls = (float*)d_out;
    float* out_reg = out_cls + (size_t)B * P * NUM_CLASSES;

    dim3 grid((P + 255) / 256, B);
    hipLaunchKernelGGL(lfd_assign, grid, dim3(256), 0, stream,
                       points, rr, gr, st, gtb, gtl, out_cls, out_reg, P);
}